// Round 15
// baseline (400.597 us; speedup 1.0000x reference)
//
#include <hip/hip_runtime.h>

#define NN 2048
#define NE 32768
#define DIM 256
#define NH 4

typedef unsigned short u16;
typedef __attribute__((ext_vector_type(4))) unsigned short u16x4;
typedef __attribute__((ext_vector_type(8))) short bf16x8;
typedef __attribute__((ext_vector_type(4))) float f32x4;

typedef __attribute__((address_space(1))) const unsigned int g_as1;
typedef __attribute__((address_space(3))) unsigned int l_as3;

__device__ __forceinline__ void gload16(const u16* g, u16* l) {
  __builtin_amdgcn_global_load_lds((g_as1*)g, (l_as3*)l, 16, 0, 0);
}

__device__ __forceinline__ u16 f2bf(float f) {
  unsigned u = __float_as_uint(f);
  unsigned r = u + 0x7FFFu + ((u >> 16) & 1u);
  return (u16)(r >> 16);
}
__device__ __forceinline__ float bf2f(u16 b) {
  return __uint_as_float(((unsigned)b) << 16);
}

// ---------------- bf16 MFMA GEMM ------------------------------------------------
struct GB { const u16* A; const int* idx; long ld; long aoffz; };

// EPI: 0 = f32 out; 1 = relu -> bf16; 2 = sigmoid -> f32;
//      4 = headsplit bf16 (rows=NE); 5 = bf16 out;
//      8 = merged pv/pq epilogue; 9 = relu(v)*extra -> f32 (node_out fusion)
template<int BNF, int EPI>
__global__ __launch_bounds__(256) void gemm_bf(
    GB ga, const u16* __restrict__ Bt, long bld, long boffz,
    const float* __restrict__ bias, void* __restrict__ Cp, long ldc, long coffz,
    int K, float scale, const float* __restrict__ extra)
{
  __shared__ u16 As[128 * 64];
  __shared__ u16 Bs[32 * BNF * 64];

  const int tid = threadIdx.x;
  const int wid = tid >> 6, lane = tid & 63;
  const int bz = blockIdx.z;
  const int m0 = blockIdx.y * 128;
  const int n0 = blockIdx.x * (32 * BNF);
  const int wr = wid >> 1, wc = wid & 1;
  const int l15 = lane & 15, l4 = lane >> 4;

  const u16* asrc[4];
  #pragma unroll
  for (int c = 0; c < 4; ++c) {
    int rl = c*32 + wid*8 + (lane >> 3);
    int row = ga.idx ? ga.idx[m0 + rl] : (m0 + rl);
    int c16s = (lane & 7) ^ (rl & 7);
    asrc[c] = ga.A + ga.aoffz * bz + (long)row * ga.ld + c16s * 8;
  }
  const u16* bsrc[BNF];
  #pragma unroll
  for (int c = 0; c < BNF; ++c) {
    int rl = c*32 + wid*8 + (lane >> 3);
    int c16s = (lane & 7) ^ (rl & 7);
    bsrc[c] = Bt + boffz * bz + (long)(n0 + rl) * bld + c16s * 8;
  }

  f32x4 acc[4][BNF] = {};

  for (int k0 = 0; k0 < K; k0 += 64) {
    #pragma unroll
    for (int c = 0; c < 4; ++c)
      gload16(asrc[c] + k0, &As[(c*32 + wid*8) * 64]);
    #pragma unroll
    for (int c = 0; c < BNF; ++c)
      gload16(bsrc[c] + k0, &Bs[(c*32 + wid*8) * 64]);
    __syncthreads();

    #pragma unroll
    for (int kk = 0; kk < 2; ++kk) {
      bf16x8 af[4], bfr[BNF];
      #pragma unroll
      for (int i = 0; i < 4; ++i) {
        int r = wr*64 + i*16 + l15;
        af[i] = *(const bf16x8*)&As[r*64 + (((kk*4 + l4) ^ (r & 7)) * 8)];
      }
      #pragma unroll
      for (int j = 0; j < BNF; ++j) {
        int r = wc*(16*BNF) + j*16 + l15;
        bfr[j] = *(const bf16x8*)&Bs[r*64 + (((kk*4 + l4) ^ (r & 7)) * 8)];
      }
      #pragma unroll
      for (int i = 0; i < 4; ++i)
        #pragma unroll
        for (int j = 0; j < BNF; ++j)
          acc[i][j] = __builtin_amdgcn_mfma_f32_16x16x32_bf16(af[i], bfr[j], acc[i][j], 0, 0, 0);
    }
    __syncthreads();
  }

  #pragma unroll
  for (int j = 0; j < BNF; ++j) {
    const int col = n0 + wc*(16*BNF) + j*16 + l15;
    const float bb = bias ? bias[col] : 0.f;
    #pragma unroll
    for (int i = 0; i < 4; ++i) {
      #pragma unroll
      for (int r = 0; r < 4; ++r) {
        const int m = m0 + wr*64 + i*16 + l4*4 + r;
        float v = acc[i][j][r] * scale + bb;
        if constexpr (EPI == 1) v = fmaxf(v, 0.f);
        if constexpr (EPI == 2) v = 1.f / (1.f + expf(-v));
        if constexpr (EPI == 9) {
          v = fmaxf(v, 0.f) * extra[(long)m*ldc + col];
          ((float*)Cp)[(long)m*ldc + col] = v;
        }
        else if constexpr (EPI == 0 || EPI == 2)
          ((float*)Cp)[coffz*bz + (long)m*ldc + col] = v;
        else if constexpr (EPI == 4)
          ((u16*)Cp)[((long)(col & 3) * NE + m) * ldc + (col >> 2) + coffz] = f2bf(v);
        else if constexpr (EPI == 8) {
          if (col < 256)
            ((float*)Cp)[(long)m*256 + (col & 3)*64 + (col >> 2)] = v;
          else {
            u16* qb = (u16*)((float*)Cp + (long)NN*256);
            int c2 = col - 256;
            qb[((long)(c2 & 3)*NN + m)*64 + (c2 >> 2)] = f2bf(v);
          }
        }
        else
          ((u16*)Cp)[coffz*bz + (long)m*ldc + col] = f2bf(v);
      }
    }
  }
}

// ---------------- fused flash MHSA with KV-split x16 (48 KB LDS) -----------------
__global__ __launch_bounds__(256) void flash_k(
    const u16* __restrict__ qkv,   // [NN][768] bf16  (q|k|v)
    const u16* __restrict__ vT,    // [256][NN] bf16  (v transposed)
    const float4* __restrict__ pk, // geo pack
    const float* __restrict__ gW1, const float* __restrict__ gb1,
    const float* __restrict__ gW2, const float* __restrict__ gb2,
    u16* __restrict__ Op,          // [16][NN][256] bf16 partial O
    float2* __restrict__ ml)       // [16][NN][4] (m,l)
{
  __shared__ u16 Kls[128*64];
  __shared__ u16 Vls[2][64*64];
  __shared__ u16 Pls[4][16*128];

  const int tid = threadIdx.x, wid = tid >> 6, lane = tid & 63;
  const int h  = blockIdx.x & 3;
  const int m0 = (blockIdx.x >> 2) * 64;
  const int part = blockIdx.y;
  const int l15 = lane & 15, l4 = lane >> 4;
  const int rl8 = wid*8 + (lane >> 3);
  const int c8  = lane & 7;

  // Q fragments directly from global (no LDS; swizzle algebra cancels)
  bf16x8 qf[2];
  {
    const u16* qp = qkv + (long)(m0 + wid*16 + l15)*768 + h*64 + l4*8;
    qf[0] = *(const bf16x8*)(qp);
    qf[1] = *(const bf16x8*)(qp + 32);
  }

  const float b10 = gb1[0], b11 = gb1[1], b12 = gb1[2];
  const float w30 = gW1[9], w31 = gW1[10], w32 = gW1[11];
  const float w20 = gW2[0*4+h], w21 = gW2[1*4+h], w22 = gW2[2*4+h];
  const float b2h = gb2[h];
  float4 rp0[4], rp1[4];
  #pragma unroll
  for (int r = 0; r < 4; ++r) {
    int qrow = m0 + wid*16 + l4*4 + r;
    rp0[r] = pk[qrow*2]; rp1[r] = pk[qrow*2 + 1];
  }

  f32x4 pa[4] = {};
  const int n0 = part*128;

  #pragma unroll
  for (int c = 0; c < 4; ++c) {
    int r = c*32 + rl8;
    gload16(qkv + (long)(n0 + r)*768 + 256 + h*64 + ((c8 ^ (r & 7))*8),
            &Kls[(c*32 + wid*8)*64]);
  }
  #pragma unroll
  for (int hh = 0; hh < 2; ++hh)
    #pragma unroll
    for (int c = 0; c < 2; ++c) {
      int r = c*32 + rl8;
      gload16(vT + (long)(h*64 + r)*NN + n0 + hh*64 + ((c8 ^ (r & 7))*8),
              &Vls[hh][(c*32 + wid*8)*64]);
    }
  __syncthreads();

  f32x4 sa[8] = {};
  #pragma unroll
  for (int kk = 0; kk < 2; ++kk) {
    #pragma unroll
    for (int j = 0; j < 8; ++j) {
      int r = j*16 + l15;
      bf16x8 bf = *(const bf16x8*)&Kls[r*64 + (((kk*4 + l4) ^ (r & 7))*8)];
      sa[j] = __builtin_amdgcn_mfma_f32_16x16x32_bf16(qf[kk], bf, sa[j], 0, 0, 0);
    }
  }

  float rowmx[4] = {-1e30f, -1e30f, -1e30f, -1e30f};
  #pragma unroll
  for (int j = 0; j < 8; ++j) {
    int n = n0 + j*16 + l15;
    float4 cp0 = pk[n*2], cp1 = pk[n*2 + 1];
    #pragma unroll
    for (int r = 0; r < 4; ++r) {
      float dot = rp0[r].x*cp0.x + rp0[r].y*cp0.y + rp0[r].z*cp0.z;
      float sq = rp0[r].w + cp0.w - 2.f*dot;
      float dist = sq > 0.f ? sq * __frsqrt_rn(sq) : 0.f;
      float h0 = fmaxf(b10 + rp1[r].x - cp1.x + dist*w30, 0.f);
      float h1 = fmaxf(b11 + rp1[r].y - cp1.y + dist*w31, 0.f);
      float h2 = fmaxf(b12 + rp1[r].z - cp1.z + dist*w32, 0.f);
      float s = sa[j][r]*0.125f + b2h + h0*w20 + h1*w21 + h2*w22;
      sa[j][r] = s;
      rowmx[r] = fmaxf(rowmx[r], s);
    }
  }
  #pragma unroll
  for (int w = 1; w < 16; w <<= 1)
    #pragma unroll
    for (int r = 0; r < 4; ++r)
      rowmx[r] = fmaxf(rowmx[r], __shfl_xor(rowmx[r], w));

  float rs[4] = {};
  #pragma unroll
  for (int j = 0; j < 8; ++j)
    #pragma unroll
    for (int r = 0; r < 4; ++r) {
      float p = __expf(sa[j][r] - rowmx[r]);
      sa[j][r] = p;
      rs[r] += p;
    }
  #pragma unroll
  for (int w = 1; w < 16; w <<= 1)
    #pragma unroll
    for (int r = 0; r < 4; ++r)
      rs[r] += __shfl_xor(rs[r], w);

  #pragma unroll
  for (int j = 0; j < 8; ++j)
    #pragma unroll
    for (int r = 0; r < 4; ++r) {
      int qr = l4*4 + r, n = j*16 + l15;
      Pls[wid][qr*128 + (((n >> 3) ^ (qr & 7))*8) + (n & 7)] = f2bf(sa[j][r]);
    }
  asm volatile("" ::: "memory");
  #pragma unroll
  for (int ks = 0; ks < 4; ++ks) {
    bf16x8 paf = *(const bf16x8*)&Pls[wid][l15*128 + (((ks*4 + l4) ^ (l15 & 7))*8)];
    #pragma unroll
    for (int j2 = 0; j2 < 4; ++j2) {
      int r = j2*16 + l15;
      bf16x8 vf = *(const bf16x8*)&Vls[ks >> 1][r*64 + ((((ks & 1)*4 + l4) ^ (r & 7))*8)];
      pa[j2] = __builtin_amdgcn_mfma_f32_16x16x32_bf16(paf, vf, pa[j2], 0, 0, 0);
    }
  }

  #pragma unroll
  for (int j2 = 0; j2 < 4; ++j2)
    #pragma unroll
    for (int r = 0; r < 4; ++r) {
      int m = m0 + wid*16 + l4*4 + r;
      Op[((long)part*NN + m)*256 + h*64 + j2*16 + l15] = f2bf(pa[j2][r]);
    }
  if (l15 == 0) {
    #pragma unroll
    for (int r = 0; r < 4; ++r) {
      int m = m0 + wid*16 + l4*4 + r;
      ml[((long)part*NN + m)*4 + h] = make_float2(rowmx[r], rs[r]);
    }
  }
}

__global__ __launch_bounds__(256) void comb_k(const u16* __restrict__ Op,
    const float2* __restrict__ ml, u16* __restrict__ attn) {
  int n = blockIdx.x, t = threadIdx.x, h = t >> 6;
  float m[16], l[16];
  #pragma unroll
  for (int p = 0; p < 16; ++p) { float2 v = ml[((long)p*NN + n)*4 + h]; m[p] = v.x; l[p] = v.y; }
  float M = m[0];
  #pragma unroll
  for (int p = 1; p < 16; ++p) M = fmaxf(M, m[p]);
  float L = 0.f, o = 0.f;
  #pragma unroll
  for (int p = 0; p < 16; ++p) {
    float w = __expf(m[p] - M);
    L += w * l[p];
    o += w * bf2f(Op[((long)p*NN + n)*256 + t]);
  }
  attn[(long)n*256 + t] = f2bf(o / L);
}

// ---------------- fused per-edge conv1d attention (1-wave, 32 edges) ------------
__global__ __launch_bounds__(64, 5) void attedge_k(
    const u16* __restrict__ qN, const u16* __restrict__ ep,
    const float* __restrict__ valNp, const int* __restrict__ ei,
    const u16* __restrict__ W1, const float* __restrict__ b1,
    const u16* __restrict__ W2, const float* __restrict__ b2,
    u16* __restrict__ msgP)
{
  __shared__ u16 As[32*128];   // 8 KB; reused as P after GEMM-1
  const int lane = threadIdx.x;
  const int h = blockIdx.y;
  const int e0 = blockIdx.x * 32;
  const int l15 = lane & 15, l4 = lane >> 4;

  #pragma unroll
  for (int p = 0; p < 8; ++p) {
    int R0 = p*4;
    int r  = R0 + (lane >> 4);
    int cd = lane & 15;
    int cs = ((cd & 7) ^ (r & 7)) | (cd & 8);
    const u16* src = (cs < 8)
        ? qN + ((long)h*NN + ei[e0 + r])*64 + cs*8
        : ep + ((long)h*NE + e0 + r)*64 + (cs & 7)*8;
    gload16(src, &As[R0*128]);
  }
  __syncthreads();

  // GEMM-1: h1 (128 cols), rows 0..31
  f32x4 acc1[2][8] = {};
  #pragma unroll
  for (int kk = 0; kk < 4; ++kk) {
    bf16x8 af[2], bfr[8];
    #pragma unroll
    for (int i = 0; i < 2; ++i) {
      int rA = i*16 + l15;
      int cg = kk*4 + l4;
      int cd = ((cg & 7) ^ (rA & 7)) | (cg & 8);
      af[i] = *(const bf16x8*)&As[rA*128 + cd*8];
    }
    #pragma unroll
    for (int j = 0; j < 8; ++j)
      bfr[j] = *(const bf16x8*)&W1[(long)(j*16 + l15)*128 + kk*32 + l4*8];
    #pragma unroll
    for (int i = 0; i < 2; ++i)
      #pragma unroll
      for (int j = 0; j < 8; ++j)
        acc1[i][j] = __builtin_amdgcn_mfma_f32_16x16x32_bf16(af[i], bfr[j], acc1[i][j], 0, 0, 0);
  }
  __syncthreads();
  #pragma unroll
  for (int i = 0; i < 2; ++i)
    #pragma unroll
    for (int j = 0; j < 8; ++j) {
      int n = j*16 + l15;
      float bb = b1[n];
      #pragma unroll
      for (int r = 0; r < 4; ++r) {
        int m = i*16 + l4*4 + r;
        int cg = n >> 3;
        int cd = ((cg & 7) ^ (m & 7)) | (cg & 8);
        As[m*128 + cd*8 + (n & 7)] = f2bf(fmaxf(acc1[i][j][r] + bb, 0.f));
      }
    }
  __syncthreads();

  // GEMM-2: s (64 cols)
  f32x4 acc2[2][4] = {};
  #pragma unroll
  for (int kk = 0; kk < 4; ++kk) {
    bf16x8 af[2], bfr[4];
    #pragma unroll
    for (int i = 0; i < 2; ++i) {
      int rA = i*16 + l15;
      int cg = kk*4 + l4;
      int cd = ((cg & 7) ^ (rA & 7)) | (cg & 8);
      af[i] = *(const bf16x8*)&As[rA*128 + cd*8];
    }
    #pragma unroll
    for (int j = 0; j < 4; ++j)
      bfr[j] = *(const bf16x8*)&W2[(long)(j*16 + l15)*128 + kk*32 + l4*8];
    #pragma unroll
    for (int i = 0; i < 2; ++i)
      #pragma unroll
      for (int j = 0; j < 4; ++j)
        acc2[i][j] = __builtin_amdgcn_mfma_f32_16x16x32_bf16(af[i], bfr[j], acc2[i][j], 0, 0, 0);
  }

  #pragma unroll
  for (int i = 0; i < 2; ++i) {
    float mx[4] = {-1e30f,-1e30f,-1e30f,-1e30f};
    #pragma unroll
    for (int j = 0; j < 4; ++j) {
      float bb = b2[j*16 + l15];
      #pragma unroll
      for (int r = 0; r < 4; ++r) {
        acc2[i][j][r] += bb;
        mx[r] = fmaxf(mx[r], acc2[i][j][r]);
      }
    }
    #pragma unroll
    for (int w = 1; w < 16; w <<= 1)
      #pragma unroll
      for (int r = 0; r < 4; ++r) mx[r] = fmaxf(mx[r], __shfl_xor(mx[r], w));
    float sum[4] = {};
    #pragma unroll
    for (int j = 0; j < 4; ++j)
      #pragma unroll
      for (int r = 0; r < 4; ++r) {
        float p = __expf(acc2[i][j][r] - mx[r]);
        acc2[i][j][r] = p; sum[r] += p;
      }
    #pragma unroll
    for (int w = 1; w < 16; w <<= 1)
      #pragma unroll
      for (int r = 0; r < 4; ++r) sum[r] += __shfl_xor(sum[r], w);
    #pragma unroll
    for (int r = 0; r < 4; ++r) {
      int m = i*16 + l4*4 + r;
      int e = e0 + m;
      int dst = ei[NE + e];
      float inv = 1.f / sum[r];
      #pragma unroll
      for (int j = 0; j < 4; ++j) {
        int o = j*16 + l15;
        float v = valNp[(long)dst*256 + h*64 + o];
        msgP[(long)e*256 + h*64 + o] = f2bf(acc2[i][j][r] * inv * v);
      }
    }
  }
}

// ---------------- ne-MLP layer-1: fused gather, dbuf 2-phase, 8 waves -----------
__global__ __launch_bounds__(512) void gemm_ne(
    const u16* __restrict__ nbf, const u16* __restrict__ ebf, const u16* __restrict__ zbuf,
    const int* __restrict__ ei, const int* __restrict__ rev,
    const u16* __restrict__ Bt, const float* __restrict__ bias, u16* __restrict__ C)
{
  __shared__ u16 As[2][128 * 64];
  __shared__ u16 Bs[2][128 * 64];
  const int tid = threadIdx.x, wid = tid >> 6, lane = tid & 63;
  const int lin = blockIdx.y * 4 + blockIdx.x;
  const int xcd = lin & 7, seq = lin >> 3;
  const int m0 = (xcd*32 + (seq >> 2)) * 128;
  const int n0 = (seq & 3) * 128;
  const int wr = wid >> 2, wc = wid & 3, l15 = lane & 15, l4 = lane >> 4;

  const u16* asrc[4][2];
  #pragma unroll
  for (int c = 0; c < 2; ++c) {
    int rl = c*64 + wid*8 + (lane >> 3);
    int m = m0 + rl;
    int c16s = ((lane & 7) ^ (rl & 7)) * 8;
    int si = ei[m], di = ei[NE + m], rv = rev[m];
    asrc[0][c] = nbf + (long)si * 256 + c16s;
    asrc[1][c] = ebf + (long)m * 256 + c16s;
    asrc[2][c] = (rv >= 0 ? ebf + (long)rv * 256 : zbuf) + c16s;
    asrc[3][c] = nbf + (long)di * 256 + c16s;
  }
  const u16* bsrc[2];
  #pragma unroll
  for (int c = 0; c < 2; ++c) {
    int rl = c*64 + wid*8 + (lane >> 3);
    int c16s = (lane & 7) ^ (rl & 7);
    bsrc[c] = Bt + (long)(n0 + rl) * 1024 + c16s * 8;
  }

  f32x4 acc[4][2] = {};

#define NE_STAGE(BUF, IT) do {                                                  \
    const int seg_ = (IT) >> 2, kt_ = (IT) & 3;                                 \
    _Pragma("unroll")                                                           \
    for (int c = 0; c < 2; ++c)                                                 \
      gload16(asrc[seg_][c] + kt_*64, &As[BUF][(c*64 + wid*8) * 64]);           \
    _Pragma("unroll")                                                           \
    for (int c = 0; c < 2; ++c)                                                 \
      gload16(bsrc[c] + seg_*256 + kt_*64, &Bs[BUF][(c*64 + wid*8) * 64]);      \
  } while (0)

  NE_STAGE(0, 0);
  #pragma unroll
  for (int it = 0; it < 16; ++it) {
    const int b = it & 1;
    if (it < 15) {
      NE_STAGE(b ^ 1, it + 1);
      asm volatile("s_waitcnt vmcnt(4)" ::: "memory");
    } else {
      asm volatile("s_waitcnt vmcnt(0)" ::: "memory");
    }
    __builtin_amdgcn_s_barrier();
    asm volatile("" ::: "memory");
    #pragma unroll
    for (int kk = 0; kk < 2; ++kk) {
      bf16x8 af[4], bfr[2];
      #pragma unroll
      for (int i = 0; i < 4; ++i) {
        int r = wr*64 + i*16 + l15;
        af[i] = *(const bf16x8*)&As[b][r*64 + (((kk*4 + l4) ^ (r & 7)) * 8)];
      }
      #pragma unroll
      for (int j = 0; j < 2; ++j) {
        int r = wc*32 + j*16 + l15;
        bfr[j] = *(const bf16x8*)&Bs[b][r*64 + (((kk*4 + l4) ^ (r & 7)) * 8)];
      }
      #pragma unroll
      for (int i = 0; i < 4; ++i)
        #pragma unroll
        for (int j = 0; j < 2; ++j)
          acc[i][j] = __builtin_amdgcn_mfma_f32_16x16x32_bf16(af[i], bfr[j], acc[i][j], 0, 0, 0);
    }
    asm volatile("" ::: "memory");
    __builtin_amdgcn_s_barrier();
  }
#undef NE_STAGE

  #pragma unroll
  for (int j = 0; j < 2; ++j) {
    const int col = n0 + wc*32 + j*16 + l15;
    const float bb = bias[col];
    #pragma unroll
    for (int i = 0; i < 4; ++i) {
      #pragma unroll
      for (int r = 0; r < 4; ++r) {
        const int m = m0 + wr*64 + i*16 + l4*4 + r;
        C[(long)m*512 + col] = f2bf(fmaxf(acc[i][j][r] + bb, 0.f));
      }
    }
  }
}

// ---------------- merged weight-prep mega-kernel --------------------------------
struct PrepEnt { const float* src; void* dst; int K; int N; int ntiles; int op; };
struct PrepDesc { PrepEnt e[24]; int n; };

__global__ __launch_bounds__(256) void wprep_k(PrepDesc d) {
  __shared__ float t[32][33];
  int b = blockIdx.x;
  int ei = 0;
  while (ei < d.n && b >= d.e[ei].ntiles) { b -= d.e[ei].ntiles; ++ei; }
  if (ei >= d.n) return;
  PrepEnt E = d.e[ei];
  int tid = threadIdx.x;
  if (E.op == 0) {                 // f32 [K][N] -> bf16 [N][K] transpose
    int kt = E.K >> 5;
    int bk = (b % kt) * 32, bn = (b / kt) * 32;
    int tx = tid & 31, ty = tid >> 5;
    #pragma unroll
    for (int i = ty; i < 32; i += 8) t[i][tx] = E.src[(long)(bk + i) * E.N + bn + tx];
    __syncthreads();
    u16* dst = (u16*)E.dst;
    #pragma unroll
    for (int i = ty; i < 32; i += 8) dst[(long)(bn + i) * E.K + bk + tx] = f2bf(t[tx][i]);
  } else if (E.op == 1) {          // f32 -> bf16 copy
    long i = (long)b * 256 + tid;
    long n4 = ((long)E.K * E.N) >> 2;
    if (i < n4) {
      float4 v = ((const float4*)E.src)[i];
      u16x4 o = { f2bf(v.x), f2bf(v.y), f2bf(v.z), f2bf(v.w) };
      ((u16x4*)E.dst)[i] = o;
    }
  } else if (E.op == 3) {          // f32 [K][256] -> bf16 rows strided 512 (prA half)
    long i = (long)b * 256 + tid;
    long n4 = ((long)E.K * E.N) >> 2;
    if (i < n4) {
      float4 v = ((const float4*)E.src)[i];
      long row = i >> 6;
      long col = (i & 63) * 4;
      u16x4 o = { f2bf(v.x), f2bf(v.y), f2bf(v.z), f2bf(v.w) };
      *(u16x4*)((u16*)E.dst + row*512 + col) = o;
    }
  } else {                          // f32 copy (bias concat)
    int i = b * 256 + tid;
    if (i < E.N) ((float*)E.dst)[i] = E.src[i];
  }
}

__global__ void geo_k(const float* __restrict__ C3, const float* __restrict__ gW1,
                      float* __restrict__ geo) {
  int n = blockIdx.x * 256 + threadIdx.x;
  if (n >= NN) return;
  float cx = C3[3*n], cy = C3[3*n+1], cz = C3[3*n+2];
  float s = cx*cx + cy*cy + cz*cz;
  float a0 = cx*gW1[0] + cy*gW1[3] + cz*gW1[6];
  float a1 = cx*gW1[1] + cy*gW1[4] + cz*gW1[7];
  float a2 = cx*gW1[2] + cy*gW1[5] + cz*gW1[8];
  float4* g = (float4*)(geo + (long)n*8);
  g[0] = make_float4(cx, cy, cz, s);
  g[1] = make_float4(a0, a1, a2, 0.f);
}

__global__ __launch_bounds__(256) void transb_k(const u16* __restrict__ src,
                                                u16* __restrict__ dst) {
  __shared__ u16 t[32][34];
  int bm = blockIdx.x * 32, bc = blockIdx.y * 32;
  int tx = threadIdx.x & 31, ty = threadIdx.x >> 5;
  #pragma unroll
  for (int i = ty; i < 32; i += 8) t[i][tx] = src[(long)(bm+i)*768 + 512 + bc + tx];
  __syncthreads();
  #pragma unroll
  for (int i = ty; i < 32; i += 8) dst[(long)(bc+i)*NN + bm + tx] = t[tx][i];
}

// ---------------- CSR build (both roles) + twin means (atomic-free) -------------
__global__ void count_k(const int* __restrict__ ei, int* __restrict__ cs,
                        int* __restrict__ cd) {
  int e = blockIdx.x * 256 + threadIdx.x;
  atomicAdd(&cs[ei[e]], 1);
  atomicAdd(&cd[ei[NE + e]], 1);
}

// grid = 2: blockIdx 0 -> src arrays, 1 -> dst arrays
__global__ __launch_bounds__(256) void scan2_k(const int* __restrict__ cnt_all,
    int* __restrict__ start_all, int* __restrict__ cursor_all) {
  const int* cnt = cnt_all + blockIdx.x * NN;
  int* start  = start_all + blockIdx.x * (NN + 1);
  int* cursor = cursor_all + blockIdx.x * NN;
  __shared__ int part[256];
  int t = threadIdx.x;
  int loc[8]; int s = 0;
  #pragma unroll
  for (int i = 0; i < 8; ++i) { int v = cnt[t*8 + i]; loc[i] = s; s += v; }
  part[t] = s;
  __syncthreads();
  if (t == 0) { int a = 0; for (int i = 0; i < 256; ++i) { int v = part[i]; part[i] = a; a += v; } }
  __syncthreads();
  int base = part[t];
  #pragma unroll
  for (int i = 0; i < 8; ++i) { start[t*8+i] = base + loc[i]; cursor[t*8+i] = base + loc[i]; }
  if (t == 255) start[NN] = base + s;
}

__global__ void scatter2_k(const int* __restrict__ ei, int* __restrict__ cur_s,
    int* __restrict__ cur_d, int* __restrict__ eids_s, int* __restrict__ eids_d) {
  int e = blockIdx.x * 256 + threadIdx.x;
  int p = atomicAdd(&cur_s[ei[e]], 1);
  eids_s[p] = e;
  int q = atomicAdd(&cur_d[ei[NE + e]], 1);
  eids_d[q] = e;
}

// reverse-edge lookup via src-CSR: rev[e] = max e' with src[e']==dst[e], dst[e']==src[e]
__global__ void rev2_k(const int* __restrict__ ei, const int* __restrict__ start_s,
    const int* __restrict__ eids_s, int* __restrict__ rev) {
  int e = blockIdx.x * 256 + threadIdx.x;
  int s = ei[e], d = ei[NE + e];
  int b = start_s[d], en = start_s[d+1];
  int best = -1;
  for (int i = b; i < en; ++i) {
    int e2 = eids_s[i];
    if (ei[NE + e2] == s) best = max(best, e2);
  }
  rev[e] = best;
}

// per (node, role): mean of edge rows; role 0 -> cols 0..255, role 1 -> 256..511
__global__ __launch_bounds__(256) void twmean_k(const u16* __restrict__ ebf,
    const int* __restrict__ start_s, const int* __restrict__ eids_s,
    const int* __restrict__ start_d, const int* __restrict__ eids_d,
    u16* __restrict__ twA)
{
  int n = blockIdx.x, t = threadIdx.x, role = blockIdx.y;
  const int* start = role ? start_d : start_s;
  const int* eids  = role ? eids_d  : eids_s;
  int b0 = start[n], e0 = start[n+1];
  float s = 0.f;
  for (int i = b0; i < e0; ++i)
    s += bf2f(ebf[(long)eids[i]*256 + t]);
  twA[(long)n*512 + role*256 + t] = f2bf(s / fmaxf((float)(e0 - b0), 1.f));
}

// per node: max over its out-edges (bf16 msg; rounding is monotone -> exact);
// writes bf16 directly into prA second half
__global__ __launch_bounds__(256) void agg_k(const int* __restrict__ start,
    const int* __restrict__ eids, const u16* __restrict__ msgP, u16* __restrict__ prA) {
  int n = blockIdx.x, t = threadIdx.x;
  int b = start[n], e_ = start[n+1];
  float mx = -1e30f;
  for (int i = b; i < e_; ++i) {
    int e = eids[i];
    mx = fmaxf(mx, bf2f(msgP[(long)e*256 + t]));
  }
  int c = (t & 63) * 4 + (t >> 6);
  prA[(long)n*512 + 256 + c] = (e_ > b) ? f2bf(mx) : f2bf(0.f);
}

// ---------------- host side ------------------------------------------------------
static GB gb(const u16* A, const int* idx, long ld, long aoffz) {
  GB g; g.A = A; g.idx = idx; g.ld = ld; g.aoffz = aoffz; return g;
}

extern "C" void kernel_launch(void* const* d_in, const int* in_sizes, int n_in,
                              void* d_out, int out_size, void* d_ws, size_t ws_size,
                              hipStream_t stream) {
  (void)in_sizes; (void)n_in; (void)out_size; (void)ws_size;

  const float* node_f = (const float*)d_in[0];
  const float* edge_f = (const float*)d_in[1];
  const float* coords = (const float*)d_in[2];
  const int*   ei     = (const int*)d_in[3];
  const float* Wq = (const float*)d_in[5];  const float* bq = (const float*)d_in[6];
  const float* Wk = (const float*)d_in[7];  const float* bk = (const float*)d_in[8];
  const float* Wv = (const float*)d_in[9];  const float* bv = (const float*)d_in[10];
  const float* Wo = (const float*)d_in[11]; const float* bo = (const float*)d_in[12];
  const float* gd_W1 = (const float*)d_in[13]; const float* gd_b1 = (const float*)d_in[14];
  const float* gd_W2 = (const float*)d_in[15]; const float* gd_b2 = (const float*)d_in[16];
  const float* tw_W1 = (const float*)d_in[17]; const float* tw_b1 = (const float*)d_in[18];
  const float* tw_W2 = (const float*)d_in[19]; const float* tw_b2 = (const float*)d_in[20];
  const float* ne_W1 = (const float*)d_in[21]; const float* ne_b1 = (const float*)d_in[22];
  const float* ne_W2 = (const float*)d_in[23]; const float* ne_b2 = (const float*)d_in[24];
  const float* att_W1 = (const float*)d_in[25]; const float* att_b1 = (const float*)d_in[26];
  const float* att_W2 = (const float*)d_in[27]; const float* att_b2 = (const float*)d_in[28];
  const float* pe_W = (const float*)d_in[29]; const float* pe_b = (const float*)d_in[30];
  const float* pq_W = (const float*)d_in[31]; const float* pq_b = (const float*)d_in[32];
  const float* pv_W = (const float*)d_in[33]; const float* pv_b = (const float*)d_in[34];
  const float* pr_W1 = (const float*)d_in[35]; const float* pr_b1 = (const float*)d_in[36];
  const float* pr_W2 = (const float*)d_in[37]; const float* pr_b2 = (const float*)d_in[38];

  char* WB = (char*)d_ws;
  float* out = (float*)d_out;
  float* out_node = out;
  float* out_edge = out + (long)NN*DIM;
  float* out_xx   = out + (long)NN*DIM + (long)NE*DIM;

  // -------- workspace --------
  const long sz_R1 = 4L*NN*NN*4;   // Opart bf16 (16.8)+ml -> msgP bf16 (16.8 MB)
  const long sz_R2 = 4L*NN*NN*2;   // nehid bf16
  const long sz_R3 = 4L*NE*128*2;  // ep bf16 (16.8) + edge_bf (16.8)
  const long R1 = 0, R2 = R1 + sz_R1, R3 = R2 + sz_R2;

  u16*    Opart = (u16*)(WB + R1);
  float2* mlbuf = (float2*)(WB + R1 + 16L*NN*256*2);
  u16*    msgP  = (u16*)(WB + R1);
  u16*   nehid  = (u16*)(WB + R2);
  u16*   ep     = (u16*)(WB + R3);                      // [4][NE][64] bf16
  u16*   edge_bf= (u16*)(WB + R3 + (long)NN*NN*4);

  long cur = R3 + sz_R3;
  auto alloc = [&](long bytes) { long o = cur; cur += (bytes + 255) & ~255L; return o; };

  // qkv_bf (3 MB) + vT (1 MB) + attn_bf (1 MB)
  long o_sub = alloc((long)NN*768*2 + (long)NN*DIM*2 + (long)NN*DIM*2);
  u16* qkv_bf  = (u16*)(WB + o_sub);        // [2048][768]
  u16* vT      = qkv_bf + (long)NN*768;     // [256][2048]
  u16* attn_bf = vT + (long)NN*DIM;         // [2048][256]

  long o_cs  = alloc(2L*NN*4);
  int* cs_i = (int*)(WB + o_cs); int* cd_i = cs_i + NN;
  long o_ea  = alloc((long)NN*DIM*4);  float* eatt = (float*)(WB + o_ea);
  long o_rv  = alloc((long)NE*4);      int* rev = (int*)(WB + o_rv);
  long o_st  = alloc(2L*(NN+1)*4);     int* start_s = (int*)(WB + o_st);
  int* start_d = start_s + (NN + 1);
  long o_cu  = alloc(2L*NN*4);         int* cursor_s = (int*)(WB + o_cu);
  int* cursor_d = cursor_s + NN;
  long o_eid = alloc(2L*NE*4);         int* eids_s = (int*)(WB + o_eid);
  int* eids_d = eids_s + NE;
  long o_zb  = alloc(1024);            u16* zbuf = (u16*)(WB + o_zb);
  long o_geo = alloc((long)NN*8*4);    float* geo = (float*)(WB + o_geo);
  long o_nbf = alloc((long)NN*DIM*2);  u16* node_bf = (u16*)(WB + o_nbf);
  long o_twA = alloc((long)NN*512*2);  u16* twA = (u16*)(WB + o_twA);
  long o_twh = alloc((long)NN*DIM*2);  u16* twh = (u16*)(WB + o_twh);
  long o_prA = alloc((long)NN*512*2);  u16* prA = (u16*)(WB + o_prA);
  long o_prh = alloc((long)NN*512*2);  u16* prh = (u16*)(WB + o_prh);
  long o_vN  = alloc((long)NN*256*4 + 4L*NN*64*2);
  float* valN = (float*)(WB + o_vN);                     // [NN][h*64+o] f32
  u16*   qN   = (u16*)(valN + (long)NN*256);             // [4][NN][64] bf16

  u16* qkv_t = (u16*)(WB + alloc(3L*DIM*DIM*2));
  u16* Wo_t  = (u16*)(WB + alloc(DIM*DIM*2));
  u16* tw1_t = (u16*)(WB + alloc(DIM*512*2));
  u16* tw2_t = (u16*)(WB + alloc(DIM*DIM*2));
  u16* ne1_t = (u16*)(WB + alloc(512L*1024*2));
  u16* ne2_t = (u16*)(WB + alloc(DIM*512*2));
  u16* pe_t  = (u16*)(WB + alloc(DIM*DIM*2));
  u16* pvq_t = (u16*)(WB + alloc(2L*DIM*DIM*2));         // [pv_t | pq_t]
  u16* pr1_t = (u16*)(WB + alloc(512L*512*2));
  u16* pr2_t = (u16*)(WB + alloc(DIM*512*2));
  u16* a1_bf = (u16*)(WB + alloc(128*128*2));
  u16* a2_bf = (u16*)(WB + alloc(64*128*2));
  float* qkvb = (float*)(WB + alloc(768*4));
  float* pvqb = (float*)(WB + alloc(512*4));

  // -------- init --------
  hipMemsetAsync(cs_i, 0, 2L*NN*4, stream);
  hipMemsetAsync(zbuf, 0, 1024, stream);

  // -------- merged weight prep --------
  PrepDesc pd{}; int ne_ = 0; int tot = 0;
  auto addT = [&](const float* s, u16* d, int K, int N) {
    pd.e[ne_] = { s, d, K, N, (K/32)*(N/32), 0 }; tot += pd.e[ne_].ntiles; ++ne_;
  };
  auto addC = [&](const float* s, u16* d, long elems) {
    int nt = (int)((elems/4 + 255) / 256);
    pd.e[ne_] = { s, d, 1, (int)elems, nt, 1 }; tot += nt; ++ne_;
  };
  auto addB = [&](const float* s, float* d, int n) {
    pd.e[ne_] = { s, d, 1, n, (n + 255)/256, 2 }; tot += pd.e[ne_].ntiles; ++ne_;
  };
  addT(Wq, qkv_t,               DIM, DIM);
  addT(Wk, qkv_t + DIM*DIM,     DIM, DIM);
  addT(Wv, qkv_t + 2*DIM*DIM,   DIM, DIM);
  addT(Wo, Wo_t, DIM, DIM);
  addT(tw_W1, tw1_t, 512, DIM);
  addT(tw_W2, tw2_t, DIM, DIM);
  addT(ne_W1, ne1_t, 1024, 512);
  addT(ne_W2, ne2_t, 512, DIM);
  addT(pe_W, pe_t, DIM, DIM);
  addT(pv_W, pvq_t,             DIM, DIM);
  addT(pq_W, pvq_t + DIM*DIM,   DIM, DIM);
  addT(pr_W1, pr1_t, 512, 512);
  addT(pr_W2, pr2_t, 512, DIM);
  addC(att_W1, a1_bf, 128*128);
  addC(att_W2, a2_bf, 64*128);
  addC(node_f, node_bf, (long)NN*DIM);
  addC(edge_f, edge_bf, (long)NE*DIM);
  addB(bq, qkvb, 256); addB(bk, qkvb + 256, 256); addB(bv, qkvb + 512, 256);
  addB(pv_b, pvqb, 256); addB(pq_b, pvqb + 256, 256);
  pd.e[ne_] = { node_f, prA, NN, 256, (int)(((long)NN*256/4 + 255)/256), 3 };
  tot += pd.e[ne_].ntiles; ++ne_;
  pd.n = ne_;
  wprep_k<<<tot, 256, 0, stream>>>(pd);
  geo_k<<<NN/256, 256, 0, stream>>>(coords, gd_W1, geo);

  // -------- CSR (both roles) + twin means + reverse-edge --------
  count_k<<<NE/256, 256, 0, stream>>>(ei, cs_i, cd_i);
  scan2_k<<<2, 256, 0, stream>>>(cs_i, start_s, cursor_s);
  scatter2_k<<<NE/256, 256, 0, stream>>>(ei, cursor_s, cursor_d, eids_s, eids_d);
  rev2_k<<<NE/256, 256, 0, stream>>>(ei, start_s, eids_s, rev);
  twmean_k<<<dim3(NN,2), 256, 0, stream>>>(edge_bf, start_s, eids_s, start_d, eids_d, twA);
  gemm_bf<4,1><<<dim3(2,16,1), 256, 0, stream>>>(gb(twA, nullptr, 512, 0), tw1_t, 512, 0,
      tw_b1, twh, DIM, 0, 512, 1.f, nullptr);
  gemm_bf<4,2><<<dim3(2,16,1), 256, 0, stream>>>(gb(twh, nullptr, DIM, 0), tw2_t, DIM, 0,
      tw_b2, eatt, DIM, 0, DIM, 1.f, nullptr);

  // -------- MHSA (flash-fused, KV-split x16) --------
  gemm_bf<4,5><<<dim3(6,16,1), 256, 0, stream>>>(gb(node_bf, nullptr, DIM, 0), qkv_t, DIM, 0,
      qkvb, qkv_bf, 768, 0, DIM, 1.f, nullptr);
  transb_k<<<dim3(64,8), 256, 0, stream>>>(qkv_bf, vT);
  flash_k<<<dim3(128,16), 256, 0, stream>>>(qkv_bf, vT, (const float4*)geo,
      gd_W1, gd_b1, gd_W2, gd_b2, Opart, mlbuf);
  comb_k<<<NN, 256, 0, stream>>>(Opart, mlbuf, attn_bf);
  gemm_bf<4,9><<<dim3(2,16,1), 256, 0, stream>>>(gb(attn_bf, nullptr, DIM, 0), Wo_t, DIM, 0,
      bo, out_node, DIM, 0, DIM, 1.f, eatt);

  // -------- edge MLP (fused gather, 2-phase dbuf, 8 waves) --------
  gemm_ne<<<dim3(4,256,1), 512, 0, stream>>>(node_bf, edge_bf, zbuf, ei, rev,
      ne1_t, ne_b1, nehid);
  gemm_bf<4,0><<<dim3(2,256,1), 256, 0, stream>>>(gb(nehid, nullptr, 512, 0), ne2_t, 512, 0,
      ne_b2, out_edge, DIM, 0, 512, 1.f, nullptr);

  // -------- per-edge attention (node-level projections + fused conv-attn) -------
  gemm_bf<4,8><<<dim3(4,16,1), 256, 0, stream>>>(gb(node_bf, nullptr, DIM, 0), pvq_t, DIM, 0,
      pvqb, valN, 256, 0, DIM, 1.f, nullptr);                           // valN + qN in one pass
  gemm_bf<4,4><<<dim3(2,256,1), 256, 0, stream>>>(gb(edge_bf, nullptr, DIM, 0), pe_t, DIM, 0,
      pe_b, ep, 64, 0, DIM, 1.f, nullptr);                              // ep [4][NE][64] bf16
  attedge_k<<<dim3(NE/32, NH), 64, 0, stream>>>(qN, ep, valN, ei,
      a1_bf, att_b1, a2_bf, att_b2, msgP);
  agg_k<<<NN, 256, 0, stream>>>(start_s, eids_s, msgP, prA);

  // -------- final node MLP --------
  gemm_bf<4,1><<<dim3(4,16,1), 256, 0, stream>>>(gb(prA, nullptr, 512, 0), pr1_t, 512, 0,
      pr_b1, prh, 512, 0, 512, 1.f, nullptr);
  gemm_bf<4,0><<<dim3(2,16,1), 256, 0, stream>>>(gb(prh, nullptr, 512, 0), pr2_t, 512, 0,
      pr_b2, out_xx, DIM, 0, 512, 1.f, nullptr);
}

// Round 16
// 377.591 us; speedup vs baseline: 1.0609x; 1.0609x over previous
//
#include <hip/hip_runtime.h>

#define NN 2048
#define NE 32768
#define DIM 256
#define NH 4

typedef unsigned short u16;
typedef __attribute__((ext_vector_type(4))) unsigned short u16x4;
typedef __attribute__((ext_vector_type(8))) short bf16x8;
typedef __attribute__((ext_vector_type(4))) float f32x4;

typedef __attribute__((address_space(1))) const unsigned int g_as1;
typedef __attribute__((address_space(3))) unsigned int l_as3;

__device__ __forceinline__ void gload16(const u16* g, u16* l) {
  __builtin_amdgcn_global_load_lds((g_as1*)g, (l_as3*)l, 16, 0, 0);
}

__device__ __forceinline__ u16 f2bf(float f) {
  unsigned u = __float_as_uint(f);
  unsigned r = u + 0x7FFFu + ((u >> 16) & 1u);
  return (u16)(r >> 16);
}
__device__ __forceinline__ float bf2f(u16 b) {
  return __uint_as_float(((unsigned)b) << 16);
}

// ---------------- bf16 MFMA GEMM ------------------------------------------------
struct GB { const u16* A; const int* idx; long ld; long aoffz; };

// EPI: 0 = f32 out; 1 = relu -> bf16; 2 = sigmoid -> f32;
//      4 = headsplit bf16 (rows=NE); 5 = bf16 out;
//      8 = merged pv/pq epilogue; 9 = relu(v)*extra -> f32 (node_out fusion)
template<int BNF, int EPI>
__global__ __launch_bounds__(256) void gemm_bf(
    GB ga, const u16* __restrict__ Bt, long bld, long boffz,
    const float* __restrict__ bias, void* __restrict__ Cp, long ldc, long coffz,
    int K, float scale, const float* __restrict__ extra)
{
  __shared__ u16 As[128 * 64];
  __shared__ u16 Bs[32 * BNF * 64];

  const int tid = threadIdx.x;
  const int wid = tid >> 6, lane = tid & 63;
  const int bz = blockIdx.z;
  const int m0 = blockIdx.y * 128;
  const int n0 = blockIdx.x * (32 * BNF);
  const int wr = wid >> 1, wc = wid & 1;
  const int l15 = lane & 15, l4 = lane >> 4;

  const u16* asrc[4];
  #pragma unroll
  for (int c = 0; c < 4; ++c) {
    int rl = c*32 + wid*8 + (lane >> 3);
    int row = ga.idx ? ga.idx[m0 + rl] : (m0 + rl);
    int c16s = (lane & 7) ^ (rl & 7);
    asrc[c] = ga.A + ga.aoffz * bz + (long)row * ga.ld + c16s * 8;
  }
  const u16* bsrc[BNF];
  #pragma unroll
  for (int c = 0; c < BNF; ++c) {
    int rl = c*32 + wid*8 + (lane >> 3);
    int c16s = (lane & 7) ^ (rl & 7);
    bsrc[c] = Bt + boffz * bz + (long)(n0 + rl) * bld + c16s * 8;
  }

  f32x4 acc[4][BNF] = {};

  for (int k0 = 0; k0 < K; k0 += 64) {
    #pragma unroll
    for (int c = 0; c < 4; ++c)
      gload16(asrc[c] + k0, &As[(c*32 + wid*8) * 64]);
    #pragma unroll
    for (int c = 0; c < BNF; ++c)
      gload16(bsrc[c] + k0, &Bs[(c*32 + wid*8) * 64]);
    __syncthreads();

    #pragma unroll
    for (int kk = 0; kk < 2; ++kk) {
      bf16x8 af[4], bfr[BNF];
      #pragma unroll
      for (int i = 0; i < 4; ++i) {
        int r = wr*64 + i*16 + l15;
        af[i] = *(const bf16x8*)&As[r*64 + (((kk*4 + l4) ^ (r & 7)) * 8)];
      }
      #pragma unroll
      for (int j = 0; j < BNF; ++j) {
        int r = wc*(16*BNF) + j*16 + l15;
        bfr[j] = *(const bf16x8*)&Bs[r*64 + (((kk*4 + l4) ^ (r & 7)) * 8)];
      }
      #pragma unroll
      for (int i = 0; i < 4; ++i)
        #pragma unroll
        for (int j = 0; j < BNF; ++j)
          acc[i][j] = __builtin_amdgcn_mfma_f32_16x16x32_bf16(af[i], bfr[j], acc[i][j], 0, 0, 0);
    }
    __syncthreads();
  }

  #pragma unroll
  for (int j = 0; j < BNF; ++j) {
    const int col = n0 + wc*(16*BNF) + j*16 + l15;
    const float bb = bias ? bias[col] : 0.f;
    #pragma unroll
    for (int i = 0; i < 4; ++i) {
      #pragma unroll
      for (int r = 0; r < 4; ++r) {
        const int m = m0 + wr*64 + i*16 + l4*4 + r;
        float v = acc[i][j][r] * scale + bb;
        if constexpr (EPI == 1) v = fmaxf(v, 0.f);
        if constexpr (EPI == 2) v = 1.f / (1.f + expf(-v));
        if constexpr (EPI == 9) {
          v = fmaxf(v, 0.f) * extra[(long)m*ldc + col];
          ((float*)Cp)[(long)m*ldc + col] = v;
        }
        else if constexpr (EPI == 0 || EPI == 2)
          ((float*)Cp)[coffz*bz + (long)m*ldc + col] = v;
        else if constexpr (EPI == 4)
          ((u16*)Cp)[((long)(col & 3) * NE + m) * ldc + (col >> 2) + coffz] = f2bf(v);
        else if constexpr (EPI == 8) {
          if (col < 256)
            ((float*)Cp)[(long)m*256 + (col & 3)*64 + (col >> 2)] = v;
          else {
            u16* qb = (u16*)((float*)Cp + (long)NN*256);
            int c2 = col - 256;
            qb[((long)(c2 & 3)*NN + m)*64 + (c2 >> 2)] = f2bf(v);
          }
        }
        else
          ((u16*)Cp)[coffz*bz + (long)m*ldc + col] = f2bf(v);
      }
    }
  }
}

// ---------------- fused flash MHSA with KV-split x16 (48 KB LDS) -----------------
__global__ __launch_bounds__(256) void flash_k(
    const u16* __restrict__ qkv,   // [NN][768] bf16  (q|k|v)
    const u16* __restrict__ vT,    // [256][NN] bf16  (v transposed)
    const float4* __restrict__ pk, // geo pack
    const float* __restrict__ gW1, const float* __restrict__ gb1,
    const float* __restrict__ gW2, const float* __restrict__ gb2,
    u16* __restrict__ Op,          // [16][NN][256] bf16 partial O
    float2* __restrict__ ml)       // [16][NN][4] (m,l)
{
  __shared__ u16 Kls[128*64];
  __shared__ u16 Vls[2][64*64];
  __shared__ u16 Pls[4][16*128];

  const int tid = threadIdx.x, wid = tid >> 6, lane = tid & 63;
  const int h  = blockIdx.x & 3;
  const int m0 = (blockIdx.x >> 2) * 64;
  const int part = blockIdx.y;
  const int l15 = lane & 15, l4 = lane >> 4;
  const int rl8 = wid*8 + (lane >> 3);
  const int c8  = lane & 7;

  // Q fragments directly from global (no LDS; swizzle algebra cancels)
  bf16x8 qf[2];
  {
    const u16* qp = qkv + (long)(m0 + wid*16 + l15)*768 + h*64 + l4*8;
    qf[0] = *(const bf16x8*)(qp);
    qf[1] = *(const bf16x8*)(qp + 32);
  }

  const float b10 = gb1[0], b11 = gb1[1], b12 = gb1[2];
  const float w30 = gW1[9], w31 = gW1[10], w32 = gW1[11];
  const float w20 = gW2[0*4+h], w21 = gW2[1*4+h], w22 = gW2[2*4+h];
  const float b2h = gb2[h];
  float4 rp0[4], rp1[4];
  #pragma unroll
  for (int r = 0; r < 4; ++r) {
    int qrow = m0 + wid*16 + l4*4 + r;
    rp0[r] = pk[qrow*2]; rp1[r] = pk[qrow*2 + 1];
  }

  f32x4 pa[4] = {};
  const int n0 = part*128;

  #pragma unroll
  for (int c = 0; c < 4; ++c) {
    int r = c*32 + rl8;
    gload16(qkv + (long)(n0 + r)*768 + 256 + h*64 + ((c8 ^ (r & 7))*8),
            &Kls[(c*32 + wid*8)*64]);
  }
  #pragma unroll
  for (int hh = 0; hh < 2; ++hh)
    #pragma unroll
    for (int c = 0; c < 2; ++c) {
      int r = c*32 + rl8;
      gload16(vT + (long)(h*64 + r)*NN + n0 + hh*64 + ((c8 ^ (r & 7))*8),
              &Vls[hh][(c*32 + wid*8)*64]);
    }
  __syncthreads();

  f32x4 sa[8] = {};
  #pragma unroll
  for (int kk = 0; kk < 2; ++kk) {
    #pragma unroll
    for (int j = 0; j < 8; ++j) {
      int r = j*16 + l15;
      bf16x8 bf = *(const bf16x8*)&Kls[r*64 + (((kk*4 + l4) ^ (r & 7))*8)];
      sa[j] = __builtin_amdgcn_mfma_f32_16x16x32_bf16(qf[kk], bf, sa[j], 0, 0, 0);
    }
  }

  float rowmx[4] = {-1e30f, -1e30f, -1e30f, -1e30f};
  #pragma unroll
  for (int j = 0; j < 8; ++j) {
    int n = n0 + j*16 + l15;
    float4 cp0 = pk[n*2], cp1 = pk[n*2 + 1];
    #pragma unroll
    for (int r = 0; r < 4; ++r) {
      float dot = rp0[r].x*cp0.x + rp0[r].y*cp0.y + rp0[r].z*cp0.z;
      float sq = rp0[r].w + cp0.w - 2.f*dot;
      float dist = sq > 0.f ? sq * __frsqrt_rn(sq) : 0.f;
      float h0 = fmaxf(b10 + rp1[r].x - cp1.x + dist*w30, 0.f);
      float h1 = fmaxf(b11 + rp1[r].y - cp1.y + dist*w31, 0.f);
      float h2 = fmaxf(b12 + rp1[r].z - cp1.z + dist*w32, 0.f);
      float s = sa[j][r]*0.125f + b2h + h0*w20 + h1*w21 + h2*w22;
      sa[j][r] = s;
      rowmx[r] = fmaxf(rowmx[r], s);
    }
  }
  #pragma unroll
  for (int w = 1; w < 16; w <<= 1)
    #pragma unroll
    for (int r = 0; r < 4; ++r)
      rowmx[r] = fmaxf(rowmx[r], __shfl_xor(rowmx[r], w));

  float rs[4] = {};
  #pragma unroll
  for (int j = 0; j < 8; ++j)
    #pragma unroll
    for (int r = 0; r < 4; ++r) {
      float p = __expf(sa[j][r] - rowmx[r]);
      sa[j][r] = p;
      rs[r] += p;
    }
  #pragma unroll
  for (int w = 1; w < 16; w <<= 1)
    #pragma unroll
    for (int r = 0; r < 4; ++r)
      rs[r] += __shfl_xor(rs[r], w);

  #pragma unroll
  for (int j = 0; j < 8; ++j)
    #pragma unroll
    for (int r = 0; r < 4; ++r) {
      int qr = l4*4 + r, n = j*16 + l15;
      Pls[wid][qr*128 + (((n >> 3) ^ (qr & 7))*8) + (n & 7)] = f2bf(sa[j][r]);
    }
  asm volatile("" ::: "memory");
  #pragma unroll
  for (int ks = 0; ks < 4; ++ks) {
    bf16x8 paf = *(const bf16x8*)&Pls[wid][l15*128 + (((ks*4 + l4) ^ (l15 & 7))*8)];
    #pragma unroll
    for (int j2 = 0; j2 < 4; ++j2) {
      int r = j2*16 + l15;
      bf16x8 vf = *(const bf16x8*)&Vls[ks >> 1][r*64 + ((((ks & 1)*4 + l4) ^ (r & 7))*8)];
      pa[j2] = __builtin_amdgcn_mfma_f32_16x16x32_bf16(paf, vf, pa[j2], 0, 0, 0);
    }
  }

  #pragma unroll
  for (int j2 = 0; j2 < 4; ++j2)
    #pragma unroll
    for (int r = 0; r < 4; ++r) {
      int m = m0 + wid*16 + l4*4 + r;
      Op[((long)part*NN + m)*256 + h*64 + j2*16 + l15] = f2bf(pa[j2][r]);
    }
  if (l15 == 0) {
    #pragma unroll
    for (int r = 0; r < 4; ++r) {
      int m = m0 + wid*16 + l4*4 + r;
      ml[((long)part*NN + m)*4 + h] = make_float2(rowmx[r], rs[r]);
    }
  }
}

__global__ __launch_bounds__(256) void comb_k(const u16* __restrict__ Op,
    const float2* __restrict__ ml, u16* __restrict__ attn) {
  int n = blockIdx.x, t = threadIdx.x, h = t >> 6;
  float m[16], l[16];
  #pragma unroll
  for (int p = 0; p < 16; ++p) { float2 v = ml[((long)p*NN + n)*4 + h]; m[p] = v.x; l[p] = v.y; }
  float M = m[0];
  #pragma unroll
  for (int p = 1; p < 16; ++p) M = fmaxf(M, m[p]);
  float L = 0.f, o = 0.f;
  #pragma unroll
  for (int p = 0; p < 16; ++p) {
    float w = __expf(m[p] - M);
    L += w * l[p];
    o += w * bf2f(Op[((long)p*NN + n)*256 + t]);
  }
  attn[(long)n*256 + t] = f2bf(o / L);
}

// ---------------- fused per-edge conv1d attention (1-wave, 32 edges) ------------
__global__ __launch_bounds__(64) void attedge_k(
    const u16* __restrict__ qN, const u16* __restrict__ ep,
    const float* __restrict__ valNp, const int* __restrict__ ei,
    const u16* __restrict__ W1, const float* __restrict__ b1,
    const u16* __restrict__ W2, const float* __restrict__ b2,
    u16* __restrict__ msgP)
{
  __shared__ u16 As[32*128];   // 8 KB; reused as P after GEMM-1
  const int lane = threadIdx.x;
  const int h = blockIdx.y;
  const int e0 = blockIdx.x * 32;
  const int l15 = lane & 15, l4 = lane >> 4;

  #pragma unroll
  for (int p = 0; p < 8; ++p) {
    int R0 = p*4;
    int r  = R0 + (lane >> 4);
    int cd = lane & 15;
    int cs = ((cd & 7) ^ (r & 7)) | (cd & 8);
    const u16* src = (cs < 8)
        ? qN + ((long)h*NN + ei[e0 + r])*64 + cs*8
        : ep + ((long)h*NE + e0 + r)*64 + (cs & 7)*8;
    gload16(src, &As[R0*128]);
  }
  __syncthreads();

  // GEMM-1: h1 (128 cols), rows 0..31
  f32x4 acc1[2][8] = {};
  #pragma unroll
  for (int kk = 0; kk < 4; ++kk) {
    bf16x8 af[2], bfr[8];
    #pragma unroll
    for (int i = 0; i < 2; ++i) {
      int rA = i*16 + l15;
      int cg = kk*4 + l4;
      int cd = ((cg & 7) ^ (rA & 7)) | (cg & 8);
      af[i] = *(const bf16x8*)&As[rA*128 + cd*8];
    }
    #pragma unroll
    for (int j = 0; j < 8; ++j)
      bfr[j] = *(const bf16x8*)&W1[(long)(j*16 + l15)*128 + kk*32 + l4*8];
    #pragma unroll
    for (int i = 0; i < 2; ++i)
      #pragma unroll
      for (int j = 0; j < 8; ++j)
        acc1[i][j] = __builtin_amdgcn_mfma_f32_16x16x32_bf16(af[i], bfr[j], acc1[i][j], 0, 0, 0);
  }
  __syncthreads();
  #pragma unroll
  for (int i = 0; i < 2; ++i)
    #pragma unroll
    for (int j = 0; j < 8; ++j) {
      int n = j*16 + l15;
      float bb = b1[n];
      #pragma unroll
      for (int r = 0; r < 4; ++r) {
        int m = i*16 + l4*4 + r;
        int cg = n >> 3;
        int cd = ((cg & 7) ^ (m & 7)) | (cg & 8);
        As[m*128 + cd*8 + (n & 7)] = f2bf(fmaxf(acc1[i][j][r] + bb, 0.f));
      }
    }
  __syncthreads();

  // GEMM-2: s (64 cols)
  f32x4 acc2[2][4] = {};
  #pragma unroll
  for (int kk = 0; kk < 4; ++kk) {
    bf16x8 af[2], bfr[4];
    #pragma unroll
    for (int i = 0; i < 2; ++i) {
      int rA = i*16 + l15;
      int cg = kk*4 + l4;
      int cd = ((cg & 7) ^ (rA & 7)) | (cg & 8);
      af[i] = *(const bf16x8*)&As[rA*128 + cd*8];
    }
    #pragma unroll
    for (int j = 0; j < 4; ++j)
      bfr[j] = *(const bf16x8*)&W2[(long)(j*16 + l15)*128 + kk*32 + l4*8];
    #pragma unroll
    for (int i = 0; i < 2; ++i)
      #pragma unroll
      for (int j = 0; j < 4; ++j)
        acc2[i][j] = __builtin_amdgcn_mfma_f32_16x16x32_bf16(af[i], bfr[j], acc2[i][j], 0, 0, 0);
  }

  #pragma unroll
  for (int i = 0; i < 2; ++i) {
    float mx[4] = {-1e30f,-1e30f,-1e30f,-1e30f};
    #pragma unroll
    for (int j = 0; j < 4; ++j) {
      float bb = b2[j*16 + l15];
      #pragma unroll
      for (int r = 0; r < 4; ++r) {
        acc2[i][j][r] += bb;
        mx[r] = fmaxf(mx[r], acc2[i][j][r]);
      }
    }
    #pragma unroll
    for (int w = 1; w < 16; w <<= 1)
      #pragma unroll
      for (int r = 0; r < 4; ++r) mx[r] = fmaxf(mx[r], __shfl_xor(mx[r], w));
    float sum[4] = {};
    #pragma unroll
    for (int j = 0; j < 4; ++j)
      #pragma unroll
      for (int r = 0; r < 4; ++r) {
        float p = __expf(acc2[i][j][r] - mx[r]);
        acc2[i][j][r] = p; sum[r] += p;
      }
    #pragma unroll
    for (int w = 1; w < 16; w <<= 1)
      #pragma unroll
      for (int r = 0; r < 4; ++r) sum[r] += __shfl_xor(sum[r], w);
    #pragma unroll
    for (int r = 0; r < 4; ++r) {
      int m = i*16 + l4*4 + r;
      int e = e0 + m;
      int dst = ei[NE + e];
      float inv = 1.f / sum[r];
      #pragma unroll
      for (int j = 0; j < 4; ++j) {
        int o = j*16 + l15;
        float v = valNp[(long)dst*256 + h*64 + o];
        msgP[(long)e*256 + h*64 + o] = f2bf(acc2[i][j][r] * inv * v);
      }
    }
  }
}

// ---------------- ne-MLP layer-1: fused gather, dbuf 2-phase, 8 waves -----------
__global__ __launch_bounds__(512) void gemm_ne(
    const u16* __restrict__ nbf, const u16* __restrict__ ebf, const u16* __restrict__ zbuf,
    const int* __restrict__ ei, const int* __restrict__ rev,
    const u16* __restrict__ Bt, const float* __restrict__ bias, u16* __restrict__ C)
{
  __shared__ u16 As[2][128 * 64];
  __shared__ u16 Bs[2][128 * 64];
  const int tid = threadIdx.x, wid = tid >> 6, lane = tid & 63;
  const int lin = blockIdx.y * 4 + blockIdx.x;
  const int xcd = lin & 7, seq = lin >> 3;
  const int m0 = (xcd*32 + (seq >> 2)) * 128;
  const int n0 = (seq & 3) * 128;
  const int wr = wid >> 2, wc = wid & 3, l15 = lane & 15, l4 = lane >> 4;

  const u16* asrc[4][2];
  #pragma unroll
  for (int c = 0; c < 2; ++c) {
    int rl = c*64 + wid*8 + (lane >> 3);
    int m = m0 + rl;
    int c16s = ((lane & 7) ^ (rl & 7)) * 8;
    int si = ei[m], di = ei[NE + m], rv = rev[m];
    asrc[0][c] = nbf + (long)si * 256 + c16s;
    asrc[1][c] = ebf + (long)m * 256 + c16s;
    asrc[2][c] = (rv >= 0 ? ebf + (long)rv * 256 : zbuf) + c16s;
    asrc[3][c] = nbf + (long)di * 256 + c16s;
  }
  const u16* bsrc[2];
  #pragma unroll
  for (int c = 0; c < 2; ++c) {
    int rl = c*64 + wid*8 + (lane >> 3);
    int c16s = (lane & 7) ^ (rl & 7);
    bsrc[c] = Bt + (long)(n0 + rl) * 1024 + c16s * 8;
  }

  f32x4 acc[4][2] = {};

#define NE_STAGE(BUF, IT) do {                                                  \
    const int seg_ = (IT) >> 2, kt_ = (IT) & 3;                                 \
    _Pragma("unroll")                                                           \
    for (int c = 0; c < 2; ++c)                                                 \
      gload16(asrc[seg_][c] + kt_*64, &As[BUF][(c*64 + wid*8) * 64]);           \
    _Pragma("unroll")                                                           \
    for (int c = 0; c < 2; ++c)                                                 \
      gload16(bsrc[c] + seg_*256 + kt_*64, &Bs[BUF][(c*64 + wid*8) * 64]);      \
  } while (0)

  NE_STAGE(0, 0);
  #pragma unroll
  for (int it = 0; it < 16; ++it) {
    const int b = it & 1;
    if (it < 15) {
      NE_STAGE(b ^ 1, it + 1);
      asm volatile("s_waitcnt vmcnt(4)" ::: "memory");
    } else {
      asm volatile("s_waitcnt vmcnt(0)" ::: "memory");
    }
    __builtin_amdgcn_s_barrier();
    asm volatile("" ::: "memory");
    #pragma unroll
    for (int kk = 0; kk < 2; ++kk) {
      bf16x8 af[4], bfr[2];
      #pragma unroll
      for (int i = 0; i < 4; ++i) {
        int r = wr*64 + i*16 + l15;
        af[i] = *(const bf16x8*)&As[b][r*64 + (((kk*4 + l4) ^ (r & 7)) * 8)];
      }
      #pragma unroll
      for (int j = 0; j < 2; ++j) {
        int r = wc*32 + j*16 + l15;
        bfr[j] = *(const bf16x8*)&Bs[b][r*64 + (((kk*4 + l4) ^ (r & 7)) * 8)];
      }
      #pragma unroll
      for (int i = 0; i < 4; ++i)
        #pragma unroll
        for (int j = 0; j < 2; ++j)
          acc[i][j] = __builtin_amdgcn_mfma_f32_16x16x32_bf16(af[i], bfr[j], acc[i][j], 0, 0, 0);
    }
    asm volatile("" ::: "memory");
    __builtin_amdgcn_s_barrier();
  }
#undef NE_STAGE

  #pragma unroll
  for (int j = 0; j < 2; ++j) {
    const int col = n0 + wc*32 + j*16 + l15;
    const float bb = bias[col];
    #pragma unroll
    for (int i = 0; i < 4; ++i) {
      #pragma unroll
      for (int r = 0; r < 4; ++r) {
        const int m = m0 + wr*64 + i*16 + l4*4 + r;
        C[(long)m*512 + col] = f2bf(fmaxf(acc[i][j][r] + bb, 0.f));
      }
    }
  }
}

// ---------------- merged weight-prep mega-kernel --------------------------------
struct PrepEnt { const float* src; void* dst; int K; int N; int ntiles; int op; };
struct PrepDesc { PrepEnt e[24]; int n; };

__global__ __launch_bounds__(256) void wprep_k(PrepDesc d) {
  __shared__ float t[32][33];
  int b = blockIdx.x;
  int ei = 0;
  while (ei < d.n && b >= d.e[ei].ntiles) { b -= d.e[ei].ntiles; ++ei; }
  if (ei >= d.n) return;
  PrepEnt E = d.e[ei];
  int tid = threadIdx.x;
  if (E.op == 0) {                 // f32 [K][N] -> bf16 [N][K] transpose
    int kt = E.K >> 5;
    int bk = (b % kt) * 32, bn = (b / kt) * 32;
    int tx = tid & 31, ty = tid >> 5;
    #pragma unroll
    for (int i = ty; i < 32; i += 8) t[i][tx] = E.src[(long)(bk + i) * E.N + bn + tx];
    __syncthreads();
    u16* dst = (u16*)E.dst;
    #pragma unroll
    for (int i = ty; i < 32; i += 8) dst[(long)(bn + i) * E.K + bk + tx] = f2bf(t[tx][i]);
  } else if (E.op == 1) {          // f32 -> bf16 copy
    long i = (long)b * 256 + tid;
    long n4 = ((long)E.K * E.N) >> 2;
    if (i < n4) {
      float4 v = ((const float4*)E.src)[i];
      u16x4 o = { f2bf(v.x), f2bf(v.y), f2bf(v.z), f2bf(v.w) };
      ((u16x4*)E.dst)[i] = o;
    }
  } else if (E.op == 3) {          // f32 [K][256] -> bf16 rows strided 512 (prA half)
    long i = (long)b * 256 + tid;
    long n4 = ((long)E.K * E.N) >> 2;
    if (i < n4) {
      float4 v = ((const float4*)E.src)[i];
      long row = i >> 6;
      long col = (i & 63) * 4;
      u16x4 o = { f2bf(v.x), f2bf(v.y), f2bf(v.z), f2bf(v.w) };
      *(u16x4*)((u16*)E.dst + row*512 + col) = o;
    }
  } else {                          // f32 copy (bias concat)
    int i = b * 256 + tid;
    if (i < E.N) ((float*)E.dst)[i] = E.src[i];
  }
}

__global__ void geo_k(const float* __restrict__ C3, const float* __restrict__ gW1,
                      float* __restrict__ geo) {
  int n = blockIdx.x * 256 + threadIdx.x;
  if (n >= NN) return;
  float cx = C3[3*n], cy = C3[3*n+1], cz = C3[3*n+2];
  float s = cx*cx + cy*cy + cz*cz;
  float a0 = cx*gW1[0] + cy*gW1[3] + cz*gW1[6];
  float a1 = cx*gW1[1] + cy*gW1[4] + cz*gW1[7];
  float a2 = cx*gW1[2] + cy*gW1[5] + cz*gW1[8];
  float4* g = (float4*)(geo + (long)n*8);
  g[0] = make_float4(cx, cy, cz, s);
  g[1] = make_float4(a0, a1, a2, 0.f);
}

__global__ __launch_bounds__(256) void transb_k(const u16* __restrict__ src,
                                                u16* __restrict__ dst) {
  __shared__ u16 t[32][34];
  int bm = blockIdx.x * 32, bc = blockIdx.y * 32;
  int tx = threadIdx.x & 31, ty = threadIdx.x >> 5;
  #pragma unroll
  for (int i = ty; i < 32; i += 8) t[i][tx] = src[(long)(bm+i)*768 + 512 + bc + tx];
  __syncthreads();
  #pragma unroll
  for (int i = ty; i < 32; i += 8) dst[(long)(bc+i)*NN + bm + tx] = t[tx][i];
}

// ---------------- CSR build (both roles) + twin means (atomic-free) -------------
__global__ void count_k(const int* __restrict__ ei, int* __restrict__ cs,
                        int* __restrict__ cd) {
  int e = blockIdx.x * 256 + threadIdx.x;
  atomicAdd(&cs[ei[e]], 1);
  atomicAdd(&cd[ei[NE + e]], 1);
}

// grid = 2: blockIdx 0 -> src arrays, 1 -> dst arrays
__global__ __launch_bounds__(256) void scan2_k(const int* __restrict__ cnt_all,
    int* __restrict__ start_all, int* __restrict__ cursor_all) {
  const int* cnt = cnt_all + blockIdx.x * NN;
  int* start  = start_all + blockIdx.x * (NN + 1);
  int* cursor = cursor_all + blockIdx.x * NN;
  __shared__ int part[256];
  int t = threadIdx.x;
  int loc[8]; int s = 0;
  #pragma unroll
  for (int i = 0; i < 8; ++i) { int v = cnt[t*8 + i]; loc[i] = s; s += v; }
  part[t] = s;
  __syncthreads();
  if (t == 0) { int a = 0; for (int i = 0; i < 256; ++i) { int v = part[i]; part[i] = a; a += v; } }
  __syncthreads();
  int base = part[t];
  #pragma unroll
  for (int i = 0; i < 8; ++i) { start[t*8+i] = base + loc[i]; cursor[t*8+i] = base + loc[i]; }
  if (t == 255) start[NN] = base + s;
}

__global__ void scatter2_k(const int* __restrict__ ei, int* __restrict__ cur_s,
    int* __restrict__ cur_d, int* __restrict__ eids_s, int* __restrict__ eids_d) {
  int e = blockIdx.x * 256 + threadIdx.x;
  int p = atomicAdd(&cur_s[ei[e]], 1);
  eids_s[p] = e;
  int q = atomicAdd(&cur_d[ei[NE + e]], 1);
  eids_d[q] = e;
}

// reverse-edge lookup via src-CSR: rev[e] = max e' with src[e']==dst[e], dst[e']==src[e]
__global__ void rev2_k(const int* __restrict__ ei, const int* __restrict__ start_s,
    const int* __restrict__ eids_s, int* __restrict__ rev) {
  int e = blockIdx.x * 256 + threadIdx.x;
  int s = ei[e], d = ei[NE + e];
  int b = start_s[d], en = start_s[d+1];
  int best = -1;
  for (int i = b; i < en; ++i) {
    int e2 = eids_s[i];
    if (ei[NE + e2] == s) best = max(best, e2);
  }
  rev[e] = best;
}

// per (node, role): mean of edge rows; role 0 -> cols 0..255, role 1 -> 256..511
__global__ __launch_bounds__(256) void twmean_k(const u16* __restrict__ ebf,
    const int* __restrict__ start_s, const int* __restrict__ eids_s,
    const int* __restrict__ start_d, const int* __restrict__ eids_d,
    u16* __restrict__ twA)
{
  int n = blockIdx.x, t = threadIdx.x, role = blockIdx.y;
  const int* start = role ? start_d : start_s;
  const int* eids  = role ? eids_d  : eids_s;
  int b0 = start[n], e0 = start[n+1];
  float s = 0.f;
  for (int i = b0; i < e0; ++i)
    s += bf2f(ebf[(long)eids[i]*256 + t]);
  twA[(long)n*512 + role*256 + t] = f2bf(s / fmaxf((float)(e0 - b0), 1.f));
}

// per node: max over its out-edges (bf16 msg; rounding is monotone -> exact);
// writes bf16 directly into prA second half
__global__ __launch_bounds__(256) void agg_k(const int* __restrict__ start,
    const int* __restrict__ eids, const u16* __restrict__ msgP, u16* __restrict__ prA) {
  int n = blockIdx.x, t = threadIdx.x;
  int b = start[n], e_ = start[n+1];
  float mx = -1e30f;
  for (int i = b; i < e_; ++i) {
    int e = eids[i];
    mx = fmaxf(mx, bf2f(msgP[(long)e*256 + t]));
  }
  int c = (t & 63) * 4 + (t >> 6);
  prA[(long)n*512 + 256 + c] = (e_ > b) ? f2bf(mx) : f2bf(0.f);
}

// ---------------- host side ------------------------------------------------------
static GB gb(const u16* A, const int* idx, long ld, long aoffz) {
  GB g; g.A = A; g.idx = idx; g.ld = ld; g.aoffz = aoffz; return g;
}

extern "C" void kernel_launch(void* const* d_in, const int* in_sizes, int n_in,
                              void* d_out, int out_size, void* d_ws, size_t ws_size,
                              hipStream_t stream) {
  (void)in_sizes; (void)n_in; (void)out_size; (void)ws_size;

  const float* node_f = (const float*)d_in[0];
  const float* edge_f = (const float*)d_in[1];
  const float* coords = (const float*)d_in[2];
  const int*   ei     = (const int*)d_in[3];
  const float* Wq = (const float*)d_in[5];  const float* bq = (const float*)d_in[6];
  const float* Wk = (const float*)d_in[7];  const float* bk = (const float*)d_in[8];
  const float* Wv = (const float*)d_in[9];  const float* bv = (const float*)d_in[10];
  const float* Wo = (const float*)d_in[11]; const float* bo = (const float*)d_in[12];
  const float* gd_W1 = (const float*)d_in[13]; const float* gd_b1 = (const float*)d_in[14];
  const float* gd_W2 = (const float*)d_in[15]; const float* gd_b2 = (const float*)d_in[16];
  const float* tw_W1 = (const float*)d_in[17]; const float* tw_b1 = (const float*)d_in[18];
  const float* tw_W2 = (const float*)d_in[19]; const float* tw_b2 = (const float*)d_in[20];
  const float* ne_W1 = (const float*)d_in[21]; const float* ne_b1 = (const float*)d_in[22];
  const float* ne_W2 = (const float*)d_in[23]; const float* ne_b2 = (const float*)d_in[24];
  const float* att_W1 = (const float*)d_in[25]; const float* att_b1 = (const float*)d_in[26];
  const float* att_W2 = (const float*)d_in[27]; const float* att_b2 = (const float*)d_in[28];
  const float* pe_W = (const float*)d_in[29]; const float* pe_b = (const float*)d_in[30];
  const float* pq_W = (const float*)d_in[31]; const float* pq_b = (const float*)d_in[32];
  const float* pv_W = (const float*)d_in[33]; const float* pv_b = (const float*)d_in[34];
  const float* pr_W1 = (const float*)d_in[35]; const float* pr_b1 = (const float*)d_in[36];
  const float* pr_W2 = (const float*)d_in[37]; const float* pr_b2 = (const float*)d_in[38];

  char* WB = (char*)d_ws;
  float* out = (float*)d_out;
  float* out_node = out;
  float* out_edge = out + (long)NN*DIM;
  float* out_xx   = out + (long)NN*DIM + (long)NE*DIM;

  // -------- workspace --------
  const long sz_R1 = 4L*NN*NN*4;   // Opart bf16 (16.8)+ml -> msgP bf16 (16.8 MB)
  const long sz_R2 = 4L*NN*NN*2;   // nehid bf16
  const long sz_R3 = 4L*NE*128*2;  // ep bf16 (16.8) + edge_bf (16.8)
  const long R1 = 0, R2 = R1 + sz_R1, R3 = R2 + sz_R2;

  u16*    Opart = (u16*)(WB + R1);
  float2* mlbuf = (float2*)(WB + R1 + 16L*NN*256*2);
  u16*    msgP  = (u16*)(WB + R1);
  u16*   nehid  = (u16*)(WB + R2);
  u16*   ep     = (u16*)(WB + R3);                      // [4][NE][64] bf16
  u16*   edge_bf= (u16*)(WB + R3 + (long)NN*NN*4);

  long cur = R3 + sz_R3;
  auto alloc = [&](long bytes) { long o = cur; cur += (bytes + 255) & ~255L; return o; };

  // qkv_bf (3 MB) + vT (1 MB) + attn_bf (1 MB)
  long o_sub = alloc((long)NN*768*2 + (long)NN*DIM*2 + (long)NN*DIM*2);
  u16* qkv_bf  = (u16*)(WB + o_sub);        // [2048][768]
  u16* vT      = qkv_bf + (long)NN*768;     // [256][2048]
  u16* attn_bf = vT + (long)NN*DIM;         // [2048][256]

  long o_cs  = alloc(2L*NN*4);
  int* cs_i = (int*)(WB + o_cs); int* cd_i = cs_i + NN;
  long o_ea  = alloc((long)NN*DIM*4);  float* eatt = (float*)(WB + o_ea);
  long o_rv  = alloc((long)NE*4);      int* rev = (int*)(WB + o_rv);
  long o_st  = alloc(2L*(NN+1)*4);     int* start_s = (int*)(WB + o_st);
  int* start_d = start_s + (NN + 1);
  long o_cu  = alloc(2L*NN*4);         int* cursor_s = (int*)(WB + o_cu);
  int* cursor_d = cursor_s + NN;
  long o_eid = alloc(2L*NE*4);         int* eids_s = (int*)(WB + o_eid);
  int* eids_d = eids_s + NE;
  long o_zb  = alloc(1024);            u16* zbuf = (u16*)(WB + o_zb);
  long o_geo = alloc((long)NN*8*4);    float* geo = (float*)(WB + o_geo);
  long o_nbf = alloc((long)NN*DIM*2);  u16* node_bf = (u16*)(WB + o_nbf);
  long o_twA = alloc((long)NN*512*2);  u16* twA = (u16*)(WB + o_twA);
  long o_twh = alloc((long)NN*DIM*2);  u16* twh = (u16*)(WB + o_twh);
  long o_prA = alloc((long)NN*512*2);  u16* prA = (u16*)(WB + o_prA);
  long o_prh = alloc((long)NN*512*2);  u16* prh = (u16*)(WB + o_prh);
  long o_vN  = alloc((long)NN*256*4 + 4L*NN*64*2);
  float* valN = (float*)(WB + o_vN);                     // [NN][h*64+o] f32
  u16*   qN   = (u16*)(valN + (long)NN*256);             // [4][NN][64] bf16

  u16* qkv_t = (u16*)(WB + alloc(3L*DIM*DIM*2));
  u16* Wo_t  = (u16*)(WB + alloc(DIM*DIM*2));
  u16* tw1_t = (u16*)(WB + alloc(DIM*512*2));
  u16* tw2_t = (u16*)(WB + alloc(DIM*DIM*2));
  u16* ne1_t = (u16*)(WB + alloc(512L*1024*2));
  u16* ne2_t = (u16*)(WB + alloc(DIM*512*2));
  u16* pe_t  = (u16*)(WB + alloc(DIM*DIM*2));
  u16* pvq_t = (u16*)(WB + alloc(2L*DIM*DIM*2));         // [pv_t | pq_t]
  u16* pr1_t = (u16*)(WB + alloc(512L*512*2));
  u16* pr2_t = (u16*)(WB + alloc(DIM*512*2));
  u16* a1_bf = (u16*)(WB + alloc(128*128*2));
  u16* a2_bf = (u16*)(WB + alloc(64*128*2));
  float* qkvb = (float*)(WB + alloc(768*4));
  float* pvqb = (float*)(WB + alloc(512*4));

  // -------- init --------
  hipMemsetAsync(cs_i, 0, 2L*NN*4, stream);
  hipMemsetAsync(zbuf, 0, 1024, stream);

  // -------- merged weight prep --------
  PrepDesc pd{}; int ne_ = 0; int tot = 0;
  auto addT = [&](const float* s, u16* d, int K, int N) {
    pd.e[ne_] = { s, d, K, N, (K/32)*(N/32), 0 }; tot += pd.e[ne_].ntiles; ++ne_;
  };
  auto addC = [&](const float* s, u16* d, long elems) {
    int nt = (int)((elems/4 + 255) / 256);
    pd.e[ne_] = { s, d, 1, (int)elems, nt, 1 }; tot += nt; ++ne_;
  };
  auto addB = [&](const float* s, float* d, int n) {
    pd.e[ne_] = { s, d, 1, n, (n + 255)/256, 2 }; tot += pd.e[ne_].ntiles; ++ne_;
  };
  addT(Wq, qkv_t,               DIM, DIM);
  addT(Wk, qkv_t + DIM*DIM,     DIM, DIM);
  addT(Wv, qkv_t + 2*DIM*DIM,   DIM, DIM);
  addT(Wo, Wo_t, DIM, DIM);
  addT(tw_W1, tw1_t, 512, DIM);
  addT(tw_W2, tw2_t, DIM, DIM);
  addT(ne_W1, ne1_t, 1024, 512);
  addT(ne_W2, ne2_t, 512, DIM);
  addT(pe_W, pe_t, DIM, DIM);
  addT(pv_W, pvq_t,             DIM, DIM);
  addT(pq_W, pvq_t + DIM*DIM,   DIM, DIM);
  addT(pr_W1, pr1_t, 512, 512);
  addT(pr_W2, pr2_t, 512, DIM);
  addC(att_W1, a1_bf, 128*128);
  addC(att_W2, a2_bf, 64*128);
  addC(node_f, node_bf, (long)NN*DIM);
  addC(edge_f, edge_bf, (long)NE*DIM);
  addB(bq, qkvb, 256); addB(bk, qkvb + 256, 256); addB(bv, qkvb + 512, 256);
  addB(pv_b, pvqb, 256); addB(pq_b, pvqb + 256, 256);
  pd.e[ne_] = { node_f, prA, NN, 256, (int)(((long)NN*256/4 + 255)/256), 3 };
  tot += pd.e[ne_].ntiles; ++ne_;
  pd.n = ne_;
  wprep_k<<<tot, 256, 0, stream>>>(pd);
  geo_k<<<NN/256, 256, 0, stream>>>(coords, gd_W1, geo);

  // -------- CSR (both roles) + twin means + reverse-edge --------
  count_k<<<NE/256, 256, 0, stream>>>(ei, cs_i, cd_i);
  scan2_k<<<2, 256, 0, stream>>>(cs_i, start_s, cursor_s);
  scatter2_k<<<NE/256, 256, 0, stream>>>(ei, cursor_s, cursor_d, eids_s, eids_d);
  rev2_k<<<NE/256, 256, 0, stream>>>(ei, start_s, eids_s, rev);
  twmean_k<<<dim3(NN,2), 256, 0, stream>>>(edge_bf, start_s, eids_s, start_d, eids_d, twA);
  gemm_bf<4,1><<<dim3(2,16,1), 256, 0, stream>>>(gb(twA, nullptr, 512, 0), tw1_t, 512, 0,
      tw_b1, twh, DIM, 0, 512, 1.f, nullptr);
  gemm_bf<4,2><<<dim3(2,16,1), 256, 0, stream>>>(gb(twh, nullptr, DIM, 0), tw2_t, DIM, 0,
      tw_b2, eatt, DIM, 0, DIM, 1.f, nullptr);

  // -------- MHSA (flash-fused, KV-split x16) --------
  gemm_bf<4,5><<<dim3(6,16,1), 256, 0, stream>>>(gb(node_bf, nullptr, DIM, 0), qkv_t, DIM, 0,
      qkvb, qkv_bf, 768, 0, DIM, 1.f, nullptr);
  transb_k<<<dim3(64,8), 256, 0, stream>>>(qkv_bf, vT);
  flash_k<<<dim3(128,16), 256, 0, stream>>>(qkv_bf, vT, (const float4*)geo,
      gd_W1, gd_b1, gd_W2, gd_b2, Opart, mlbuf);
  comb_k<<<NN, 256, 0, stream>>>(Opart, mlbuf, attn_bf);
  gemm_bf<4,9><<<dim3(2,16,1), 256, 0, stream>>>(gb(attn_bf, nullptr, DIM, 0), Wo_t, DIM, 0,
      bo, out_node, DIM, 0, DIM, 1.f, eatt);

  // -------- edge MLP (fused gather, 2-phase dbuf, 8 waves) --------
  gemm_ne<<<dim3(4,256,1), 512, 0, stream>>>(node_bf, edge_bf, zbuf, ei, rev,
      ne1_t, ne_b1, nehid);
  gemm_bf<4,0><<<dim3(2,256,1), 256, 0, stream>>>(gb(nehid, nullptr, 512, 0), ne2_t, 512, 0,
      ne_b2, out_edge, DIM, 0, 512, 1.f, nullptr);

  // -------- per-edge attention (node-level projections + fused conv-attn) -------
  gemm_bf<4,8><<<dim3(4,16,1), 256, 0, stream>>>(gb(node_bf, nullptr, DIM, 0), pvq_t, DIM, 0,
      pvqb, valN, 256, 0, DIM, 1.f, nullptr);                           // valN + qN in one pass
  gemm_bf<4,4><<<dim3(2,256,1), 256, 0, stream>>>(gb(edge_bf, nullptr, DIM, 0), pe_t, DIM, 0,
      pe_b, ep, 64, 0, DIM, 1.f, nullptr);                              // ep [4][NE][64] bf16
  attedge_k<<<dim3(NE/32, NH), 64, 0, stream>>>(qN, ep, valN, ei,
      a1_bf, att_b1, a2_bf, att_b2, msgP);
  agg_k<<<NN, 256, 0, stream>>>(start_s, eids_s, msgP, prA);

  // -------- final node MLP --------
  gemm_bf<4,1><<<dim3(4,16,1), 256, 0, stream>>>(gb(prA, nullptr, 512, 0), pr1_t, 512, 0,
      pr_b1, prh, 512, 0, 512, 1.f, nullptr);
  gemm_bf<4,0><<<dim3(2,16,1), 256, 0, stream>>>(gb(prh, nullptr, 512, 0), pr2_t, 512, 0,
      pr_b2, out_xx, DIM, 0, 512, 1.f, nullptr);
}